// Round 2
// baseline (663.399 us; speedup 1.0000x reference)
//
#include <hip/hip_runtime.h>
#include <stdint.h>

#define NVOX 400000
#define KTAPS 27
#define TILE 128
#define CAP 1024
#define NCHUNK_CAP (CAP / 16 + KTAPS)   // 91

typedef __bf16 bf16x8 __attribute__((ext_vector_type(8)));
typedef float floatx4 __attribute__((ext_vector_type(4)));

__device__ __forceinline__ uint32_t f2bf(float f) {
  uint32_t u = __builtin_bit_cast(uint32_t, f);
  u += 0x7fffu + ((u >> 16) & 1u);
  return u >> 16;
}

// Weight convert + transpose: Wt[k][co][ci] = bf16(W[k][ci][co]). 432 blocks.
__global__ void k_wt(const float* __restrict__ W, unsigned short* __restrict__ Wt) {
  int i = blockIdx.x * 256 + threadIdx.x;
  int k = i >> 12;
  int rem = i & 4095;
  int ci = rem >> 6;
  int co = rem & 63;
  Wt[(k << 12) + (co << 6) + ci] = (unsigned short)f2bf(W[i]);
}

// Sparse gather-GEMM conv, wave-autonomous chunks (no inner barriers).
// Block = 128 output voxels, 256 threads = 4 waves. Compaction builds per-tap
// (row, idx) pair lists; chunks of <=16 rows are distributed round-robin to
// waves. A wave gathers its chunk's A rows DIRECTLY into the 16x16x32 MFMA
// A-fragment (lane l -> row l&15, ci-slice l>>4), multiplies against all 64
// couts of W[k] (8 MFMAs), and scatter-adds D into a shared LDS accumulator
// via ds-atomics (waves may share output rows across taps).
__global__ __launch_bounds__(256, 3) void k_conv(
    const float* __restrict__ feats,
    const unsigned short* __restrict__ Wt,     // [k][co][ci] bf16
    const float* __restrict__ bias,
    const int* __restrict__ nbr,               // [27][NVOX]
    float* __restrict__ out) {                 // [NVOX][64]

  __shared__ alignas(16) float accS[TILE * 72];          // 36864 B, pitch 72 (bank spread)
  __shared__ int pairIdx[CAP];                           // 4096 B
  __shared__ unsigned short pairRow[CAP];                // 2048 B
  __shared__ unsigned long long masksS[KTAPS * 2];       // 432 B
  __shared__ int woff[KTAPS * 2 + 1];                    // 220 B
  __shared__ unsigned int chunkTab[NCHUNK_CAP];          // 364 B: k<<16 | start<<5 | len
  __shared__ int nChunksS;

  const int t = threadIdx.x;
  const int w = t >> 6;
  const int l = t & 63;

  // Bijective chunked XCD swizzle (m204): consecutive work -> same XCD L2.
  const int nwg = gridDim.x;
  const int q = nwg >> 3, r8 = nwg & 7;
  const int xcd = blockIdx.x & 7, hi = blockIdx.x >> 3;
  const int wg = (xcd < r8 ? xcd * (q + 1) : r8 * (q + 1) + (xcd - r8) * q) + hi;
  const int v0 = wg * TILE;

  // zero accumulator
  {
    float4 z = make_float4(0.f, 0.f, 0.f, 0.f);
    float4* a4 = (float4*)accS;
#pragma unroll
    for (int i = 0; i < 9; ++i) a4[t + i * 256] = z;
  }

  // ---- compaction pass 1: ballot masks per (tap, wave) ----
#pragma unroll
  for (int k = 0; k < KTAPS; ++k) {
    int id = (t < TILE) ? nbr[(size_t)k * NVOX + v0 + t] : -1;
    unsigned long long m = __ballot(id >= 0);
    if (l == 0 && w < 2) masksS[k * 2 + w] = m;
  }
  __syncthreads();
  // exclusive prefix over the 54 (tap,wave) counts -> pair offsets (wave 0)
  if (w == 0) {
    int c = (l < KTAPS * 2) ? __popcll(masksS[l]) : 0;
#pragma unroll
    for (int d = 1; d < 64; d <<= 1) { int o = __shfl_up(c, d); if (l >= d) c += o; }
    if (l < KTAPS * 2) woff[l + 1] = c;
    if (l == 0) woff[0] = 0;
  }
  __syncthreads();
  // ---- compaction pass 2: write (row, idx) pairs grouped by tap ----
#pragma unroll
  for (int k = 0; k < KTAPS; ++k) {
    int id = (t < TILE) ? nbr[(size_t)k * NVOX + v0 + t] : -1;
    if (id >= 0) {
      unsigned long long m = masksS[k * 2 + w];
      int pos = woff[k * 2 + w] + __popcll(m & ((1ull << l) - 1ull));
      if (pos < CAP) { pairRow[pos] = (unsigned short)t; pairIdx[pos] = id; }
    }
  }
  // chunk table: tap k -> ceil(cnt/16) chunks of <=16 rows (wave 0)
  if (w == 0) {
    int b0 = 0, cnt = 0;
    if (l < KTAPS) {
      b0 = min(woff[2 * l], CAP);
      cnt = min(woff[2 * l + 2], CAP) - b0;
    }
    int nch = (cnt + 15) >> 4;
    int inc = nch;
#pragma unroll
    for (int d = 1; d < 64; d <<= 1) { int o = __shfl_up(inc, d); if (l >= d) inc += o; }
    int base = inc - nch;
    for (int j = 0; j < nch; ++j) {
      int st = b0 + 16 * j;
      int ln = min(16, cnt - 16 * j);
      chunkTab[base + j] = ((unsigned)l << 16) | ((unsigned)st << 5) | (unsigned)ln;
    }
    if (l == KTAPS - 1) nChunksS = inc;
  }
  __syncthreads();
  const int nc = nChunksS;

  const int r16 = l & 15;   // A row within chunk / B cout-within-tile
  const int hk = l >> 4;    // 8-channel ci slice (fragment K position)

  // Stage chunk c: gather A frags straight from global, load B frags from Wt.
  auto stageF = [&](int c, int& stS, int& lnS, uint4& a0, uint4& a1,
                    uint4& b0, uint4& b1, uint4& b2, uint4& b3,
                    uint4& b4, uint4& b5, uint4& b6, uint4& b7) {
    unsigned meta = chunkTab[c];
    int kk = (int)(meta >> 16);
    int st = (int)((meta >> 5) & 0x7FFu);
    int ln = (int)(meta & 31u);
    stS = st; lnS = ln;
    int idx = (r16 < ln) ? pairIdx[st + r16] : 0;   // clamped: garbage rows never scattered
    const float* s = feats + (size_t)idx * 64 + hk * 8;
    float4 f0 = *(const float4*)s;
    float4 f1 = *(const float4*)(s + 4);
    float4 f2 = *(const float4*)(s + 32);
    float4 f3 = *(const float4*)(s + 36);
    uint4 A;
    A.x = f2bf(f0.x) | (f2bf(f0.y) << 16);
    A.y = f2bf(f0.z) | (f2bf(f0.w) << 16);
    A.z = f2bf(f1.x) | (f2bf(f1.y) << 16);
    A.w = f2bf(f1.z) | (f2bf(f1.w) << 16);
    a0 = A;
    A.x = f2bf(f2.x) | (f2bf(f2.y) << 16);
    A.y = f2bf(f2.z) | (f2bf(f2.w) << 16);
    A.z = f2bf(f3.x) | (f2bf(f3.y) << 16);
    A.w = f2bf(f3.z) | (f2bf(f3.w) << 16);
    a1 = A;
    // B[q][h]: co = q*16 + r16, ci = h*32 + hk*8
    const unsigned short* bp = Wt + (kk << 12) + r16 * 64 + hk * 8;
    b0 = *(const uint4*)bp;
    b1 = *(const uint4*)(bp + 32);
    b2 = *(const uint4*)(bp + 1024);
    b3 = *(const uint4*)(bp + 1056);
    b4 = *(const uint4*)(bp + 2048);
    b5 = *(const uint4*)(bp + 2080);
    b6 = *(const uint4*)(bp + 3072);
    b7 = *(const uint4*)(bp + 3104);
  };

  // Compute chunk: 8 MFMAs + guarded scatter-add into accS (LDS atomics).
  auto computeF = [&](int st, int ln, uint4 a0u, uint4 a1u,
                      uint4 b0, uint4 b1, uint4 b2, uint4 b3,
                      uint4 b4, uint4 b5, uint4 b6, uint4 b7) {
    bf16x8 a0 = __builtin_bit_cast(bf16x8, a0u);
    bf16x8 a1 = __builtin_bit_cast(bf16x8, a1u);
    floatx4 z = {0.f, 0.f, 0.f, 0.f};
    floatx4 d0 = __builtin_amdgcn_mfma_f32_16x16x32_bf16(a0, __builtin_bit_cast(bf16x8, b0), z, 0, 0, 0);
    d0 = __builtin_amdgcn_mfma_f32_16x16x32_bf16(a1, __builtin_bit_cast(bf16x8, b1), d0, 0, 0, 0);
    floatx4 d1 = __builtin_amdgcn_mfma_f32_16x16x32_bf16(a0, __builtin_bit_cast(bf16x8, b2), z, 0, 0, 0);
    d1 = __builtin_amdgcn_mfma_f32_16x16x32_bf16(a1, __builtin_bit_cast(bf16x8, b3), d1, 0, 0, 0);
    floatx4 d2 = __builtin_amdgcn_mfma_f32_16x16x32_bf16(a0, __builtin_bit_cast(bf16x8, b4), z, 0, 0, 0);
    d2 = __builtin_amdgcn_mfma_f32_16x16x32_bf16(a1, __builtin_bit_cast(bf16x8, b5), d2, 0, 0, 0);
    floatx4 d3 = __builtin_amdgcn_mfma_f32_16x16x32_bf16(a0, __builtin_bit_cast(bf16x8, b6), z, 0, 0, 0);
    d3 = __builtin_amdgcn_mfma_f32_16x16x32_bf16(a1, __builtin_bit_cast(bf16x8, b7), d3, 0, 0, 0);
    // D layout (m89): col = l&15 (cout-in-tile), row = (l>>4)*4 + reg
#pragma unroll
    for (int j2 = 0; j2 < 4; ++j2) {
      int r2 = hk * 4 + j2;
      if (r2 < ln) {
        int tr = pairRow[st + r2];
        float* p = accS + tr * 72 + r16;
        atomicAdd(p, d0[j2]);
        atomicAdd(p + 16, d1[j2]);
        atomicAdd(p + 32, d2[j2]);
        atomicAdd(p + 48, d3[j2]);
      }
    }
  };

  // ---- wave-private chunk loop, 2-deep alternating register pipeline ----
  {
    int c = w;
    int s0 = 0, n0 = 0, s1 = 0, n1 = 0;
    uint4 a00, a01, b00, b01, b02, b03, b04, b05, b06, b07;
    uint4 a10, a11, b10, b11, b12, b13, b14, b15, b16, b17;
    if (c < nc) {
      stageF(c, s0, n0, a00, a01, b00, b01, b02, b03, b04, b05, b06, b07);
      while (true) {
        int cn = c + 4;
        if (cn < nc) stageF(cn, s1, n1, a10, a11, b10, b11, b12, b13, b14, b15, b16, b17);
        computeF(s0, n0, a00, a01, b00, b01, b02, b03, b04, b05, b06, b07);
        c = cn;
        if (c >= nc) break;
        cn = c + 4;
        if (cn < nc) stageF(cn, s0, n0, a00, a01, b00, b01, b02, b03, b04, b05, b06, b07);
        computeF(s1, n1, a10, a11, b10, b11, b12, b13, b14, b15, b16, b17);
        c = cn;
        if (c >= nc) break;
      }
    }
  }

  // ---- epilogue: out = acc + bias (coalesced float4) ----
  __syncthreads();
  {
    int vox = t >> 1;
    int cb = (t & 1) * 32;
    float* op = out + (size_t)(v0 + vox) * 64 + cb;
    const float* ap = accS + vox * 72 + cb;
#pragma unroll
    for (int qq = 0; qq < 8; ++qq) {
      float4 v = *(const float4*)(ap + qq * 4);
      float4 bv = *(const float4*)(bias + cb + qq * 4);
      v.x += bv.x; v.y += bv.y; v.z += bv.z; v.w += bv.w;
      *(float4*)(op + qq * 4) = v;
    }
  }
}

extern "C" void kernel_launch(void* const* d_in, const int* in_sizes, int n_in,
                              void* d_out, int out_size, void* d_ws, size_t ws_size,
                              hipStream_t stream) {
  const float* feats  = (const float*)d_in[0];
  const float* weight = (const float*)d_in[1];
  const float* bias   = (const float*)d_in[2];
  const int*   nbr    = (const int*)d_in[3];
  float* out = (float*)d_out;

  unsigned short* Wt = (unsigned short*)d_ws;   // 27*4096*2 = 221184 B

  k_wt<<<432, 256, 0, stream>>>(weight, Wt);
  k_conv<<<NVOX / TILE, 256, 0, stream>>>(feats, Wt, bias, nbr, out);
}